// Round 10
// baseline (29973.990 us; speedup 1.0000x reference)
//
#include <hip/hip_runtime.h>

// Reservoir forward, R10 = R6 skeleton with barrier-free per-wave self-staging.
//   Epoch-tagged u64 state words ((epoch<<32)|f32) exchanged via relaxed
//   agent-scope atomics (L2-served polls, IF-resolved stores — R6 evidence).
//   NEW vs R6 (single structural change): each wave polls the exact 32 words
//   its own dot-products need (sbuf[lane+64k]) straight into registers.
//   -> no LDS staging, no __syncthreads, waves fully decoupled.
//   Safety: producer reaches step t+1 only after all waves consumed t-1
//   (publish-after-read chain) => no overwrite-before-read, no future tags.
//   Spin: sequential spin on word 0 (absorbs straggler wait), then burst
//   reload + joint re-check for words 1..31 (~1 extra RT, vs R6's ~3).

typedef unsigned long long u64;

#define NRES 2048
#define NIN  64
#define NOUT 16
#define TT   4096
#define GWG  128           // workgroups
#define BTH  512           // threads per wg (8 waves)
#define ROWS_PER_WG 16     // NRES / GWG, 2 rows per wave
#define KPL  32            // state/W words per lane (NRES/64)

__global__ void init_ws(u64* statebuf) {
    int i = blockIdx.x * blockDim.x + threadIdx.x;
    if (i < NRES)            statebuf[i] = 0ull;                   // buf0: epoch 0, value 0
    else if (i < 2 * NRES)   statebuf[i] = 0xFFFFFFFF00000000ull;  // buf1: invalid epoch
}

__launch_bounds__(BTH, 2)   // VGPR cap 256; W(64) + polls(64) + misc fits
__global__ void reservoir_run(const float* __restrict__ inputs,
                              const float* __restrict__ outputs,
                              const float* __restrict__ noise,
                              const float* __restrict__ w,
                              const float* __restrict__ w_in,
                              const float* __restrict__ w_feedb,
                              u64* statebuf)
{
    const int wg   = blockIdx.x;      // 0..127
    const int tid  = threadIdx.x;     // 0..511
    const int wave = tid >> 6;        // 0..7
    const int lane = tid & 63;
    const int row0 = wg * ROWS_PER_WG + wave * 2;   // wave owns rows row0, row0+1

    // ---- W rows into VGPRs, ELEMENT layout matching the polled words:
    //      wreg[k] multiplies state column (lane + 64k) ----
    const float* wr0 = w + (size_t)(row0 + 0) * NRES;
    const float* wr1 = w + (size_t)(row0 + 1) * NRES;
    float wreg0[KPL], wreg1[KPL];
#pragma unroll
    for (int k = 0; k < KPL; ++k) {
        wreg0[k] = wr0[lane + 64 * k];
        wreg1[k] = wr1[lane + 64 * k];
    }
    // pin: block rematerialization (R3's failure mode)
#pragma unroll
    for (int k = 0; k < KPL; ++k) {
        asm volatile("" : "+v"(wreg0[k]), "+v"(wreg1[k]));
    }
    const float wi0 = w_in[(row0 + 0) * NIN + lane];
    const float wi1 = w_in[(row0 + 1) * NIN + lane];
    const float wf0 = (lane < NOUT) ? w_feedb[(row0 + 0) * NOUT + lane] : 0.0f;
    const float wf1 = (lane < NOUT) ? w_feedb[(row0 + 1) * NOUT + lane] : 0.0f;

    // software-pipelined externals
    float inp_c = inputs[1 * NIN + lane];
    float po_c  = (lane < NOUT) ? outputs[0 * NOUT + lane] : 0.0f;
    float nz_c  = (lane < 2) ? noise[(size_t)1 * NRES + row0 + lane] : 0.0f;

    for (int t = 1; t < TT; ++t) {
        const u64* sbuf = statebuf + ((t - 1) & 1) * NRES;
        u64*       dbuf = statebuf + (t & 1) * NRES;
        const unsigned want = (unsigned)(t - 1);

        const float b0 = fmaf(wf0, po_c, wi0 * inp_c);
        const float b1 = fmaf(wf1, po_c, wi1 * inp_c);
        const float nz = nz_c;

        // ---- issue all 32 poll loads (coalesced 512B per k, all in flight) ----
        u64 p[KPL];
#pragma unroll
        for (int k = 0; k < KPL; ++k)
            p[k] = __hip_atomic_load(&sbuf[lane + 64 * k], __ATOMIC_RELAXED,
                                     __HIP_MEMORY_SCOPE_AGENT);

        // ---- sequential spin on word 0: absorbs the straggler wait ----
        while ((unsigned)(p[0] >> 32) != want)
            p[0] = __hip_atomic_load(&sbuf[lane], __ATOMIC_RELAXED,
                                     __HIP_MEMORY_SCOPE_AGENT);

        // ---- remainder: burst-reload stale words, joint re-check ----
        for (;;) {
            bool allok = true;
#pragma unroll
            for (int k = 1; k < KPL; ++k) {
                if ((unsigned)(p[k] >> 32) != want) {
                    p[k] = __hip_atomic_load(&sbuf[lane + 64 * k], __ATOMIC_RELAXED,
                                             __HIP_MEMORY_SCOPE_AGENT);
                    allok = false;
                }
            }
            if (allok) break;
        }

        // prefetch next step's externals (hide under FMA phase)
        if (t + 1 < TT) {
            inp_c = inputs[(t + 1) * NIN + lane];
            po_c  = (lane < NOUT) ? outputs[t * NOUT + lane] : 0.0f;
            nz_c  = (lane < 2) ? noise[(size_t)(t + 1) * NRES + row0 + lane] : 0.0f;
        }

        // ---- 2 row dot-products straight from polled registers ----
        float a0 = b0, a1 = b1;
#pragma unroll
        for (int k = 0; k < KPL; ++k) {
            float sv = __uint_as_float((unsigned)p[k]);
            a0 = fmaf(wreg0[k], sv, a0);
            a1 = fmaf(wreg1[k], sv, a1);
        }

        // ---- paired reduction: 6 shuffles; even lanes -> a0 sum, odd -> a1 ----
        float c = (lane & 1) ? a1 : a0;
        float d = (lane & 1) ? a0 : a1;
        c += __shfl_xor(d, 1, 64);
#pragma unroll
        for (int off = 2; off <= 32; off <<= 1) c += __shfl_xor(c, off, 64);

        float ns = tanhf(c) + nz;      // all lanes compute; only 0,1 used
        if (lane < 2) {
            u64 pk = ((u64)(unsigned)t << 32) | (u64)__float_as_uint(ns);
            __hip_atomic_store(&dbuf[row0 + lane], pk, __ATOMIC_RELAXED,
                               __HIP_MEMORY_SCOPE_AGENT);
        }
    }
}

__global__ void epilogue(const u64* __restrict__ statebuf,
                         const float* __restrict__ inputs,
                         const float* __restrict__ outputs,
                         const float* __restrict__ w_out,
                         float* __restrict__ out)
{
    const u64* sb = statebuf + ((TT - 1) & 1) * NRES;   // state(4095) in buf 1
    const int tid  = threadIdx.x;   // 1024 threads = 16 waves
    const int wave = tid >> 6;
    const int lane = tid & 63;

    float acc = 0.0f;
#pragma unroll
    for (int k = 0; k < NRES / 64; ++k) {
        int r = lane + 64 * k;
        acc = fmaf(__uint_as_float((unsigned)sb[r]), w_out[r * NOUT + wave], acc);
    }
#pragma unroll
    for (int off = 32; off; off >>= 1) acc += __shfl_xor(acc, off, 64);
    if (lane == 0) out[wave] = acc;

    for (int i = tid; i < NRES; i += 1024)
        out[NOUT + i] = __uint_as_float((unsigned)sb[i]);
    if (tid < NIN)  out[NOUT + NRES + tid]       = inputs[(TT - 1) * NIN + tid];
    if (tid < NOUT) out[NOUT + NRES + NIN + tid] = outputs[(TT - 2) * NOUT + tid];
}

extern "C" void kernel_launch(void* const* d_in, const int* in_sizes, int n_in,
                              void* d_out, int out_size, void* d_ws, size_t ws_size,
                              hipStream_t stream) {
    const float* inputs  = (const float*)d_in[0];   // (4096, 64)
    const float* outputs = (const float*)d_in[1];   // (4096, 16)
    const float* noise   = (const float*)d_in[2];   // (4096, 2048)
    const float* w       = (const float*)d_in[3];   // (2048, 2048)
    const float* w_in    = (const float*)d_in[4];   // (2048, 64)
    const float* w_feedb = (const float*)d_in[5];   // (2048, 16)
    const float* w_out   = (const float*)d_in[6];   // (2048, 16)
    float* out = (float*)d_out;                     // 16 + 2128 floats

    u64* statebuf = (u64*)d_ws;                     // 2 * 2048 u64 = 32 KB

    init_ws<<<dim3(8), dim3(512), 0, stream>>>(statebuf);
    reservoir_run<<<dim3(GWG), dim3(BTH), 0, stream>>>(inputs, outputs, noise,
                                                       w, w_in, w_feedb, statebuf);
    epilogue<<<dim3(1), dim3(1024), 0, stream>>>(statebuf, inputs, outputs, w_out, out);
}

// Round 11
// 8591.463 us; speedup vs baseline: 3.4888x; 3.4888x over previous
//
#include <hip/hip_runtime.h>

// Reservoir forward, R11 = R6 protocol, doubled width (256 wgs, 1 row/wave).
//   Epoch-tagged u64 state words ((epoch<<32)|f32), relaxed agent-scope atomics.
//   Per-thread protocol IDENTICAL to R6 (best: 7.63ms): 4 poll words, simple
//   sequential spins, LDS stage, one barrier, FMA, butterfly reduce, publish.
//   Changed: GWG 128->256 (all CUs), ROWS_PER_WG 16->8, rows/wave 2->1
//   -> FMA + reduction phase halves; protocol term unchanged.
//   Lessons: R7/R8/R9/R10 all mutated the poll/publish protocol and regressed;
//   do not touch it again.

typedef unsigned long long u64;

#define NRES 2048
#define NIN  64
#define NOUT 16
#define TT   4096
#define GWG  256           // workgroups (all CUs)
#define BTH  512           // threads per wg (8 waves)
#define ROWS_PER_WG 8      // NRES / GWG, 1 row per wave
#define NJ 8               // float4 blocks per lane (32 cols)

__global__ void init_ws(u64* statebuf) {
    int i = blockIdx.x * blockDim.x + threadIdx.x;
    if (i < NRES)            statebuf[i] = 0ull;                   // buf0: epoch 0, value 0
    else if (i < 2 * NRES)   statebuf[i] = 0xFFFFFFFF00000000ull;  // buf1: invalid epoch
}

__launch_bounds__(BTH, 2)
__global__ void reservoir_run(const float* __restrict__ inputs,
                              const float* __restrict__ outputs,
                              const float* __restrict__ noise,
                              const float* __restrict__ w,
                              const float* __restrict__ w_in,
                              const float* __restrict__ w_feedb,
                              u64* statebuf)
{
    const int wg   = blockIdx.x;      // 0..255
    const int tid  = threadIdx.x;     // 0..511
    const int wave = tid >> 6;        // 0..7
    const int lane = tid & 63;
    const int row  = wg * ROWS_PER_WG + wave;   // this wave owns one row

    // ---- W row into VGPRs: 8 float4 = 32 regs/thread ----
    const float4* wr = (const float4*)(w + (size_t)row * NRES);
    float4 wv[NJ];
#pragma unroll
    for (int j = 0; j < NJ; ++j) wv[j] = wr[64 * j + lane];
    // pin: block rematerialization (R3's failure mode)
#pragma unroll
    for (int j = 0; j < NJ; ++j)
        asm volatile("" : "+v"(wv[j].x), "+v"(wv[j].y), "+v"(wv[j].z), "+v"(wv[j].w));

    const float wi = w_in[row * NIN + lane];
    const float wf = (lane < NOUT) ? w_feedb[row * NOUT + lane] : 0.0f;

    __shared__ float s_state[2][NRES];   // 16 KB parity double buffer

    // software-pipelined externals
    float inp_c = inputs[1 * NIN + lane];
    float po_c  = (lane < NOUT) ? outputs[0 * NOUT + lane] : 0.0f;
    float nz_c  = (lane == 0) ? noise[(size_t)1 * NRES + row] : 0.0f;

    for (int t = 1; t < TT; ++t) {
        const u64* sbuf = statebuf + ((t - 1) & 1) * NRES;
        u64*       dbuf = statebuf + (t & 1) * NRES;
        float*     sl   = s_state[(t - 1) & 1];
        const unsigned want = (unsigned)(t - 1);

        float a0 = fmaf(wf, po_c, wi * inp_c);
        const float nz = nz_c;

        // ---- poll-stage state(t-1): 4 u64/thread, all in flight, R6 spins ----
        u64 p0 = __hip_atomic_load(&sbuf[tid],        __ATOMIC_RELAXED, __HIP_MEMORY_SCOPE_AGENT);
        u64 p1 = __hip_atomic_load(&sbuf[tid +  512], __ATOMIC_RELAXED, __HIP_MEMORY_SCOPE_AGENT);
        u64 p2 = __hip_atomic_load(&sbuf[tid + 1024], __ATOMIC_RELAXED, __HIP_MEMORY_SCOPE_AGENT);
        u64 p3 = __hip_atomic_load(&sbuf[tid + 1536], __ATOMIC_RELAXED, __HIP_MEMORY_SCOPE_AGENT);
        while ((unsigned)(p0 >> 32) != want)
            p0 = __hip_atomic_load(&sbuf[tid],        __ATOMIC_RELAXED, __HIP_MEMORY_SCOPE_AGENT);
        while ((unsigned)(p1 >> 32) != want)
            p1 = __hip_atomic_load(&sbuf[tid +  512], __ATOMIC_RELAXED, __HIP_MEMORY_SCOPE_AGENT);
        while ((unsigned)(p2 >> 32) != want)
            p2 = __hip_atomic_load(&sbuf[tid + 1024], __ATOMIC_RELAXED, __HIP_MEMORY_SCOPE_AGENT);
        while ((unsigned)(p3 >> 32) != want)
            p3 = __hip_atomic_load(&sbuf[tid + 1536], __ATOMIC_RELAXED, __HIP_MEMORY_SCOPE_AGENT);
        sl[tid]        = __uint_as_float((unsigned)p0);
        sl[tid +  512] = __uint_as_float((unsigned)p1);
        sl[tid + 1024] = __uint_as_float((unsigned)p2);
        sl[tid + 1536] = __uint_as_float((unsigned)p3);
        __syncthreads();

        // prefetch next step's externals (hide under FMA phase)
        if (t + 1 < TT) {
            inp_c = inputs[(t + 1) * NIN + lane];
            po_c  = (lane < NOUT) ? outputs[t * NOUT + lane] : 0.0f;
            nz_c  = (lane == 0) ? noise[(size_t)(t + 1) * NRES + row] : 0.0f;
        }

        // ---- 1 row dot-product, float4 LDS reads (ds_read_b128) ----
        const float4* s4 = (const float4*)sl;
#pragma unroll
        for (int j = 0; j < NJ; ++j) {
            float4 sv = s4[64 * j + lane];
            a0 = fmaf(wv[j].x, sv.x, a0); a0 = fmaf(wv[j].y, sv.y, a0);
            a0 = fmaf(wv[j].z, sv.z, a0); a0 = fmaf(wv[j].w, sv.w, a0);
        }

        // ---- butterfly reduction: 6 shuffles, all lanes end with the sum ----
#pragma unroll
        for (int off = 32; off; off >>= 1) a0 += __shfl_xor(a0, off, 64);

        float ns = tanhf(a0) + nz;     // all lanes compute; lane 0 publishes
        if (lane == 0) {
            u64 pk = ((u64)(unsigned)t << 32) | (u64)__float_as_uint(ns);
            __hip_atomic_store(&dbuf[row], pk, __ATOMIC_RELAXED,
                               __HIP_MEMORY_SCOPE_AGENT);
        }
    }
}

__global__ void epilogue(const u64* __restrict__ statebuf,
                         const float* __restrict__ inputs,
                         const float* __restrict__ outputs,
                         const float* __restrict__ w_out,
                         float* __restrict__ out)
{
    const u64* sb = statebuf + ((TT - 1) & 1) * NRES;   // state(4095) in buf 1
    const int tid  = threadIdx.x;   // 1024 threads = 16 waves
    const int wave = tid >> 6;
    const int lane = tid & 63;

    float acc = 0.0f;
#pragma unroll
    for (int k = 0; k < NRES / 64; ++k) {
        int r = lane + 64 * k;
        acc = fmaf(__uint_as_float((unsigned)sb[r]), w_out[r * NOUT + wave], acc);
    }
#pragma unroll
    for (int off = 32; off; off >>= 1) acc += __shfl_xor(acc, off, 64);
    if (lane == 0) out[wave] = acc;

    for (int i = tid; i < NRES; i += 1024)
        out[NOUT + i] = __uint_as_float((unsigned)sb[i]);
    if (tid < NIN)  out[NOUT + NRES + tid]       = inputs[(TT - 1) * NIN + tid];
    if (tid < NOUT) out[NOUT + NRES + NIN + tid] = outputs[(TT - 2) * NOUT + tid];
}

extern "C" void kernel_launch(void* const* d_in, const int* in_sizes, int n_in,
                              void* d_out, int out_size, void* d_ws, size_t ws_size,
                              hipStream_t stream) {
    const float* inputs  = (const float*)d_in[0];   // (4096, 64)
    const float* outputs = (const float*)d_in[1];   // (4096, 16)
    const float* noise   = (const float*)d_in[2];   // (4096, 2048)
    const float* w       = (const float*)d_in[3];   // (2048, 2048)
    const float* w_in    = (const float*)d_in[4];   // (2048, 64)
    const float* w_feedb = (const float*)d_in[5];   // (2048, 16)
    const float* w_out   = (const float*)d_in[6];   // (2048, 16)
    float* out = (float*)d_out;                     // 16 + 2128 floats

    u64* statebuf = (u64*)d_ws;                     // 2 * 2048 u64 = 32 KB

    init_ws<<<dim3(8), dim3(512), 0, stream>>>(statebuf);
    reservoir_run<<<dim3(GWG), dim3(BTH), 0, stream>>>(inputs, outputs, noise,
                                                       w, w_in, w_feedb, statebuf);
    epilogue<<<dim3(1), dim3(1024), 0, stream>>>(statebuf, inputs, outputs, w_out, out);
}

// Round 12
// 7690.483 us; speedup vs baseline: 3.8975x; 1.1172x over previous
//
#include <hip/hip_runtime.h>

// Reservoir forward, R12 = R6 verbatim (best: 7.63 ms, 1.86 us/step).
//   Epoch-tagged u64 state exchange (value|epoch) via relaxed agent-scope
//   atomics resolving at the Infinity Cache. 128 wgs x 512 thr, 2 rows/wave,
//   W in VGPRs (64 regs/thread), float4 LDS staging, paired 6-shuffle reduce.
//   Width sweep: 32wg=7.3us, 64wg=4.0, 128wg=1.86, 256wg=2.10 per step ->
//   128 is the minimum. Protocol mutations R7-R11 all regressed; this is the
//   final structure (sync-latency bound: 4095 serial IF exchanges).

typedef unsigned long long u64;

#define NRES 2048
#define NIN  64
#define NOUT 16
#define TT   4096
#define GWG  128           // workgroups
#define BTH  512           // threads per wg (8 waves)
#define ROWS_PER_WG 16     // NRES / GWG, 2 rows per wave
#define NJ 8               // float4 blocks per lane (32 cols)

__global__ void init_ws(u64* statebuf) {
    int i = blockIdx.x * blockDim.x + threadIdx.x;
    if (i < NRES)            statebuf[i] = 0ull;                   // buf0: epoch 0, value 0
    else if (i < 2 * NRES)   statebuf[i] = 0xFFFFFFFF00000000ull;  // buf1: invalid epoch
}

__launch_bounds__(BTH, 2)   // 2 waves/SIMD min -> VGPR cap 256 (W fits in regs)
__global__ void reservoir_run(const float* __restrict__ inputs,
                              const float* __restrict__ outputs,
                              const float* __restrict__ noise,
                              const float* __restrict__ w,
                              const float* __restrict__ w_in,
                              const float* __restrict__ w_feedb,
                              u64* statebuf)
{
    const int wg   = blockIdx.x;      // 0..127
    const int tid  = threadIdx.x;     // 0..511
    const int wave = tid >> 6;        // 0..7
    const int lane = tid & 63;
    const int row0 = wg * ROWS_PER_WG + wave * 2;   // wave owns rows row0, row0+1

    // ---- W rows into VGPRs: 2 rows x 8 float4 = 64 regs/thread ----
    const float4* wr0 = (const float4*)(w + (size_t)(row0 + 0) * NRES);
    const float4* wr1 = (const float4*)(w + (size_t)(row0 + 1) * NRES);
    float4 wv0[NJ], wv1[NJ];
#pragma unroll
    for (int j = 0; j < NJ; ++j) {
        wv0[j] = wr0[64 * j + lane];
        wv1[j] = wr1[64 * j + lane];
    }
    // pin: block rematerialization (R3's failure mode)
#pragma unroll
    for (int j = 0; j < NJ; ++j) {
        asm volatile("" : "+v"(wv0[j].x), "+v"(wv0[j].y), "+v"(wv0[j].z), "+v"(wv0[j].w));
        asm volatile("" : "+v"(wv1[j].x), "+v"(wv1[j].y), "+v"(wv1[j].z), "+v"(wv1[j].w));
    }
    const float wi0 = w_in[(row0 + 0) * NIN + lane];
    const float wi1 = w_in[(row0 + 1) * NIN + lane];
    const float wf0 = (lane < NOUT) ? w_feedb[(row0 + 0) * NOUT + lane] : 0.0f;
    const float wf1 = (lane < NOUT) ? w_feedb[(row0 + 1) * NOUT + lane] : 0.0f;

    __shared__ float s_state[2][NRES];   // 16 KB parity double buffer

    // software-pipelined externals
    float inp_c = inputs[1 * NIN + lane];
    float po_c  = (lane < NOUT) ? outputs[0 * NOUT + lane] : 0.0f;
    float nz_c  = (lane < 2) ? noise[(size_t)1 * NRES + row0 + lane] : 0.0f;

    for (int t = 1; t < TT; ++t) {
        const u64* sbuf = statebuf + ((t - 1) & 1) * NRES;
        u64*       dbuf = statebuf + (t & 1) * NRES;
        float*     sl   = s_state[(t - 1) & 1];
        const unsigned want = (unsigned)(t - 1);

        float a0 = fmaf(wf0, po_c, wi0 * inp_c);
        float a1 = fmaf(wf1, po_c, wi1 * inp_c);
        const float nz = nz_c;

        // ---- poll-stage state(t-1): 4 u64 per thread, all loads in flight ----
        u64 p0 = __hip_atomic_load(&sbuf[tid],        __ATOMIC_RELAXED, __HIP_MEMORY_SCOPE_AGENT);
        u64 p1 = __hip_atomic_load(&sbuf[tid +  512], __ATOMIC_RELAXED, __HIP_MEMORY_SCOPE_AGENT);
        u64 p2 = __hip_atomic_load(&sbuf[tid + 1024], __ATOMIC_RELAXED, __HIP_MEMORY_SCOPE_AGENT);
        u64 p3 = __hip_atomic_load(&sbuf[tid + 1536], __ATOMIC_RELAXED, __HIP_MEMORY_SCOPE_AGENT);
        while ((unsigned)(p0 >> 32) != want)
            p0 = __hip_atomic_load(&sbuf[tid],        __ATOMIC_RELAXED, __HIP_MEMORY_SCOPE_AGENT);
        while ((unsigned)(p1 >> 32) != want)
            p1 = __hip_atomic_load(&sbuf[tid +  512], __ATOMIC_RELAXED, __HIP_MEMORY_SCOPE_AGENT);
        while ((unsigned)(p2 >> 32) != want)
            p2 = __hip_atomic_load(&sbuf[tid + 1024], __ATOMIC_RELAXED, __HIP_MEMORY_SCOPE_AGENT);
        while ((unsigned)(p3 >> 32) != want)
            p3 = __hip_atomic_load(&sbuf[tid + 1536], __ATOMIC_RELAXED, __HIP_MEMORY_SCOPE_AGENT);
        sl[tid]        = __uint_as_float((unsigned)p0);
        sl[tid +  512] = __uint_as_float((unsigned)p1);
        sl[tid + 1024] = __uint_as_float((unsigned)p2);
        sl[tid + 1536] = __uint_as_float((unsigned)p3);
        __syncthreads();

        // prefetch next step's externals (hide under FMA phase)
        if (t + 1 < TT) {
            inp_c = inputs[(t + 1) * NIN + lane];
            po_c  = (lane < NOUT) ? outputs[t * NOUT + lane] : 0.0f;
            nz_c  = (lane < 2) ? noise[(size_t)(t + 1) * NRES + row0 + lane] : 0.0f;
        }

        // ---- 2 row dot-products, float4 LDS reads (ds_read_b128) ----
        const float4* s4 = (const float4*)sl;
#pragma unroll
        for (int j = 0; j < NJ; ++j) {
            float4 sv = s4[64 * j + lane];
            a0 = fmaf(wv0[j].x, sv.x, a0); a0 = fmaf(wv0[j].y, sv.y, a0);
            a0 = fmaf(wv0[j].z, sv.z, a0); a0 = fmaf(wv0[j].w, sv.w, a0);
            a1 = fmaf(wv1[j].x, sv.x, a1); a1 = fmaf(wv1[j].y, sv.y, a1);
            a1 = fmaf(wv1[j].z, sv.z, a1); a1 = fmaf(wv1[j].w, sv.w, a1);
        }

        // ---- paired reduction: 6 shuffles for both rows ----
        // even lanes carry a0-chain, odd lanes carry a1-chain
        float c = (lane & 1) ? a1 : a0;
        float d = (lane & 1) ? a0 : a1;
        c += __shfl_xor(d, 1, 64);
#pragma unroll
        for (int off = 2; off <= 32; off <<= 1) c += __shfl_xor(c, off, 64);
        // lane 0: full a0 sum; lane 1: full a1 sum

        float ns = tanhf(c) + nz;      // all lanes compute; only 0,1 used
        if (lane < 2) {
            u64 pk = ((u64)(unsigned)t << 32) | (u64)__float_as_uint(ns);
            __hip_atomic_store(&dbuf[row0 + lane], pk, __ATOMIC_RELAXED,
                               __HIP_MEMORY_SCOPE_AGENT);
        }
    }
}

__global__ void epilogue(const u64* __restrict__ statebuf,
                         const float* __restrict__ inputs,
                         const float* __restrict__ outputs,
                         const float* __restrict__ w_out,
                         float* __restrict__ out)
{
    const u64* sb = statebuf + ((TT - 1) & 1) * NRES;   // state(4095) in buf 1
    const int tid  = threadIdx.x;   // 1024 threads = 16 waves
    const int wave = tid >> 6;
    const int lane = tid & 63;

    float acc = 0.0f;
#pragma unroll
    for (int k = 0; k < NRES / 64; ++k) {
        int r = lane + 64 * k;
        acc = fmaf(__uint_as_float((unsigned)sb[r]), w_out[r * NOUT + wave], acc);
    }
#pragma unroll
    for (int off = 32; off; off >>= 1) acc += __shfl_xor(acc, off, 64);
    if (lane == 0) out[wave] = acc;

    for (int i = tid; i < NRES; i += 1024)
        out[NOUT + i] = __uint_as_float((unsigned)sb[i]);
    if (tid < NIN)  out[NOUT + NRES + tid]       = inputs[(TT - 1) * NIN + tid];
    if (tid < NOUT) out[NOUT + NRES + NIN + tid] = outputs[(TT - 2) * NOUT + tid];
}

extern "C" void kernel_launch(void* const* d_in, const int* in_sizes, int n_in,
                              void* d_out, int out_size, void* d_ws, size_t ws_size,
                              hipStream_t stream) {
    const float* inputs  = (const float*)d_in[0];   // (4096, 64)
    const float* outputs = (const float*)d_in[1];   // (4096, 16)
    const float* noise   = (const float*)d_in[2];   // (4096, 2048)
    const float* w       = (const float*)d_in[3];   // (2048, 2048)
    const float* w_in    = (const float*)d_in[4];   // (2048, 64)
    const float* w_feedb = (const float*)d_in[5];   // (2048, 16)
    const float* w_out   = (const float*)d_in[6];   // (2048, 16)
    float* out = (float*)d_out;                     // 16 + 2128 floats

    u64* statebuf = (u64*)d_ws;                     // 2 * 2048 u64 = 32 KB

    init_ws<<<dim3(8), dim3(512), 0, stream>>>(statebuf);
    reservoir_run<<<dim3(GWG), dim3(BTH), 0, stream>>>(inputs, outputs, noise,
                                                       w, w_in, w_feedb, statebuf);
    epilogue<<<dim3(1), dim3(1024), 0, stream>>>(statebuf, inputs, outputs, w_out, out);
}